// Round 2
// baseline (250.727 us; speedup 1.0000x reference)
//
#include <hip/hip_runtime.h>

// Problem constants (from reference setup_inputs)
#define BB  16
#define LL  100
#define LOC 2000
#define EE  16

// SU=500, SL=0, TU=3600, TL=0
__global__ __launch_bounds__(256) void embed_kernel(
    const int*   __restrict__ traj_loc,   // (B,L)
    const float* __restrict__ mat2,       // (LOC,LOC)
    const float* __restrict__ vec,        // (B,L)
    const int*   __restrict__ traj_len,   // (B,)
    const float* __restrict__ emb_sl,     // (2,E)
    const float* __restrict__ emb_su,     // (2,E)
    const float* __restrict__ emb_tl,     // (2,E)
    const float* __restrict__ emb_tu,     // (2,E)
    float*       __restrict__ out)        // (B,L,LOC,E)
{
    __shared__ float s_row[LOC];          // 8 KB — one mat2 row (already masked)

    const int bl = blockIdx.x;            // 0 .. B*L-1
    const int b  = bl / LL;
    const int l  = bl - b * LL;

    const bool valid = l < traj_len[b];
    const int  m     = valid ? 1 : 0;

    int row = traj_loc[bl] - 1;
    row = min(max(row, 0), LOC - 1);

    const float dt = vec[bl];
    const float wt = dt * (1.0f / 3600.0f);   // dt/(TU-TL)

    const int tid = threadIdx.x;

    // ---- Stage the row into LDS (coalesced float4 loads, masked by valid) ----
    const float4* __restrict__ row4 = reinterpret_cast<const float4*>(mat2 + (size_t)row * LOC);
    float4* __restrict__ s_row4 = reinterpret_cast<float4*>(s_row);
    for (int i = tid; i < LOC / 4; i += 256) {          // 500 float4s
        float4 v;
        if (valid) {
            v = row4[i];
        } else {
            v.x = v.y = v.z = v.w = 0.0f;
        }
        s_row4[i] = v;
    }

    // ---- Per-(b,l) constants: out[j,e] = base[e] + coef[e] * ds[j] ----
    const int e0 = (tid & 3) * 4;         // this thread's 4 consecutive e's
    const int j0 = tid >> 2;              // 0..63  (j lane)

    float base[4], coef[4];
    #pragma unroll
    for (int k = 0; k < 4; ++k) {
        const int e  = e0 + k;
        const float sl = emb_sl[m * EE + e];
        const float su = emb_su[m * EE + e];
        const float tl = emb_tl[m * EE + e];
        const float tu = emb_tu[m * EE + e];
        base[k] = sl + tl * (1.0f - wt) + tu * wt;
        coef[k] = (su - sl) * (1.0f / 500.0f); // /(SU-SL)
    }

    __syncthreads();

    // ---- Stream stores: LDS read (broadcast, conflict-free) -> FMA -> float4 store ----
    float* __restrict__ outp = out + (size_t)bl * LOC * EE;

    #pragma unroll 4
    for (int j = j0; j < LOC; j += 64) {
        const float ds = s_row[j];
        float4 v;
        v.x = base[0] + coef[0] * ds;
        v.y = base[1] + coef[1] * ds;
        v.z = base[2] + coef[2] * ds;
        v.w = base[3] + coef[3] * ds;
        *reinterpret_cast<float4*>(outp + (size_t)j * EE + e0) = v;
    }
}

extern "C" void kernel_launch(void* const* d_in, const int* in_sizes, int n_in,
                              void* d_out, int out_size, void* d_ws, size_t ws_size,
                              hipStream_t stream) {
    const int*   traj_loc = (const int*)  d_in[0];
    const float* mat2     = (const float*)d_in[1];
    const float* vec      = (const float*)d_in[2];
    const int*   traj_len = (const int*)  d_in[3];
    const float* emb_sl   = (const float*)d_in[4];
    const float* emb_su   = (const float*)d_in[5];
    const float* emb_tl   = (const float*)d_in[6];
    const float* emb_tu   = (const float*)d_in[7];
    float* out = (float*)d_out;

    embed_kernel<<<BB * LL, 256, 0, stream>>>(
        traj_loc, mat2, vec, traj_len, emb_sl, emb_su, emb_tl, emb_tu, out);
}

// Round 4
// 240.353 us; speedup vs baseline: 1.0432x; 1.0432x over previous
//
#include <hip/hip_runtime.h>

// Problem constants (from reference setup_inputs)
#define BB  16
#define LL  100
#define LOC 2000
#define EE  16

typedef float vfloat4 __attribute__((ext_vector_type(4)));  // native vec for nt-store

// out[bl,j,e] = base[e] + coef[e] * mat2[row(bl), j]
//   base[e] = sl[m,e] + tl[m,e]*(1-wt) + tu[m,e]*wt,  wt = vec[bl]/3600
//   coef[e] = valid ? (su[m,e]-sl[m,e])/500 : 0        (ds masked via coef)
__global__ __launch_bounds__(256) void embed_kernel(
    const int*   __restrict__ traj_loc,   // (B,L)
    const float* __restrict__ mat2,       // (LOC,LOC)
    const float* __restrict__ vec,        // (B,L)
    const int*   __restrict__ traj_len,   // (B,)
    const float* __restrict__ emb_sl,     // (2,E)
    const float* __restrict__ emb_su,     // (2,E)
    const float* __restrict__ emb_tl,     // (2,E)
    const float* __restrict__ emb_tu,     // (2,E)
    float*       __restrict__ out)        // (B,L,LOC,E)
{
    const int bl = blockIdx.x;            // 0 .. B*L-1
    const int b  = bl / LL;
    const int l  = bl - b * LL;

    const bool valid = l < traj_len[b];
    const int  m     = valid ? 1 : 0;

    int row = traj_loc[bl] - 1;
    row = min(max(row, 0), LOC - 1);      // always a safe row; masking via coef

    const float dt = vec[bl];
    const float wt = dt * (1.0f / 3600.0f);

    const int tid = threadIdx.x;
    const int e0  = (tid & 3) * 4;        // this thread's 4 consecutive e's
    const int j0  = tid >> 2;             // 0..63  (j lane)

    float base[4], coef[4];
    const float cs = valid ? (1.0f / 500.0f) : 0.0f;
    #pragma unroll
    for (int k = 0; k < 4; ++k) {
        const int e  = e0 + k;
        const float sl = emb_sl[m * EE + e];
        const float su = emb_su[m * EE + e];
        const float tl = emb_tl[m * EE + e];
        const float tu = emb_tu[m * EE + e];
        base[k] = sl + tl * (1.0f - wt) + tu * wt;
        coef[k] = (su - sl) * cs;         // 0 when invalid -> ds ignored
    }

    const float* __restrict__ rowp = mat2 + (size_t)row * LOC;
    float*       __restrict__ outp = out  + (size_t)bl * (LOC * EE) + e0;

    // Branchless body: load (L2-hot), 4 FMA, nontemporal float4 store.
    // unroll 8 -> 8 loads in flight per waitcnt batch (break serial chain).
    #pragma unroll 8
    for (int j = j0; j < LOC; j += 64) {
        const float ds = rowp[j];
        vfloat4 v;
        v.x = base[0] + coef[0] * ds;
        v.y = base[1] + coef[1] * ds;
        v.z = base[2] + coef[2] * ds;
        v.w = base[3] + coef[3] * ds;
        __builtin_nontemporal_store(v, reinterpret_cast<vfloat4*>(outp + (size_t)j * EE));
    }
}

extern "C" void kernel_launch(void* const* d_in, const int* in_sizes, int n_in,
                              void* d_out, int out_size, void* d_ws, size_t ws_size,
                              hipStream_t stream) {
    const int*   traj_loc = (const int*)  d_in[0];
    const float* mat2     = (const float*)d_in[1];
    const float* vec      = (const float*)d_in[2];
    const int*   traj_len = (const int*)  d_in[3];
    const float* emb_sl   = (const float*)d_in[4];
    const float* emb_su   = (const float*)d_in[5];
    const float* emb_tl   = (const float*)d_in[6];
    const float* emb_tu   = (const float*)d_in[7];
    float* out = (float*)d_out;

    embed_kernel<<<BB * LL, 256, 0, stream>>>(
        traj_loc, mat2, vec, traj_len, emb_sl, emb_su, emb_tl, emb_tu, out);
}

// Round 5
// 236.126 us; speedup vs baseline: 1.0618x; 1.0179x over previous
//
#include <hip/hip_runtime.h>

// Problem constants (from reference setup_inputs)
#define BB  16
#define LL  100
#define LOC 2000
#define EE  16

typedef float vfloat4 __attribute__((ext_vector_type(4)));

// out[bl,j,e] = base[e] + coef[e] * mat2[row(bl), j]
//   base[e] = sl[m,e] + tl[m,e]*(1-wt) + tu[m,e]*wt,  wt = vec[bl]/3600
//   coef[e] = valid ? (su[m,e]-sl[m,e])/500 : 0        (ds masked via coef)
//
// Structure: preload ALL row values into registers -> single vmcnt drain ->
// pure store stream (no loads in the store loop => no vmcnt mixing; stores
// stream like fillBuffer).
__global__ __launch_bounds__(256) void embed_kernel(
    const int*   __restrict__ traj_loc,   // (B,L)
    const float* __restrict__ mat2,       // (LOC,LOC)
    const float* __restrict__ vec,        // (B,L)
    const int*   __restrict__ traj_len,   // (B,)
    const float* __restrict__ emb_sl,     // (2,E)
    const float* __restrict__ emb_su,     // (2,E)
    const float* __restrict__ emb_tl,     // (2,E)
    const float* __restrict__ emb_tu,     // (2,E)
    float*       __restrict__ out)        // (B,L,LOC,E)
{
    const int bl = blockIdx.x;            // 0 .. B*L-1
    const int b  = bl / LL;
    const int l  = bl - b * LL;

    const bool valid = l < traj_len[b];
    const int  m     = valid ? 1 : 0;

    int row = traj_loc[bl] - 1;
    row = min(max(row, 0), LOC - 1);      // safe row; masking via coef

    const float dt = vec[bl];
    const float wt = dt * (1.0f / 3600.0f);

    const int tid = threadIdx.x;
    const int e0  = (tid & 3) * 4;        // this thread's 4 consecutive e's
    const int j0  = tid >> 2;             // 0..63  (j lane)

    const float* __restrict__ rowp = mat2 + (size_t)row * LOC;

    // ---- Batch ALL loads first (emb tables + 32 row values), one drain ----
    float base[4], coef[4];
    const float cs = valid ? (1.0f / 500.0f) : 0.0f;
    #pragma unroll
    for (int k = 0; k < 4; ++k) {
        const int e  = e0 + k;
        const float sl = emb_sl[m * EE + e];
        const float su = emb_su[m * EE + e];
        const float tl = emb_tl[m * EE + e];
        const float tu = emb_tu[m * EE + e];
        base[k] = sl + tl * (1.0f - wt) + tu * wt;
        coef[k] = (su - sl) * cs;         // 0 when invalid
    }

    // 2000 = 31*64 + 16: k<31 uniform for all lanes; k=31 only for j0<16.
    float ds[32];
    #pragma unroll
    for (int k = 0; k < 31; ++k)
        ds[k] = rowp[j0 + 64 * k];
    ds[31] = rowp[min(j0 + 31 * 64, LOC - 1)];   // clamped (avoids OOB), store predicated

    // ---- Pure store stream: addr = base + tid*16B + k*4KB ----
    // (j0*EE + e0 == tid*4 floats; each k-step covers 64 j's * 16 e = 4 KB)
    float* __restrict__ outp = out + (size_t)bl * (LOC * EE) + tid * 4;

    #pragma unroll
    for (int k = 0; k < 31; ++k) {
        vfloat4 v;
        v.x = base[0] + coef[0] * ds[k];
        v.y = base[1] + coef[1] * ds[k];
        v.z = base[2] + coef[2] * ds[k];
        v.w = base[3] + coef[3] * ds[k];
        __builtin_nontemporal_store(v, reinterpret_cast<vfloat4*>(outp + k * 1024));
    }
    if (j0 < 16) {                        // wave-uniform (only wave 0)
        vfloat4 v;
        v.x = base[0] + coef[0] * ds[31];
        v.y = base[1] + coef[1] * ds[31];
        v.z = base[2] + coef[2] * ds[31];
        v.w = base[3] + coef[3] * ds[31];
        __builtin_nontemporal_store(v, reinterpret_cast<vfloat4*>(outp + 31 * 1024));
    }
}

extern "C" void kernel_launch(void* const* d_in, const int* in_sizes, int n_in,
                              void* d_out, int out_size, void* d_ws, size_t ws_size,
                              hipStream_t stream) {
    const int*   traj_loc = (const int*)  d_in[0];
    const float* mat2     = (const float*)d_in[1];
    const float* vec      = (const float*)d_in[2];
    const int*   traj_len = (const int*)  d_in[3];
    const float* emb_sl   = (const float*)d_in[4];
    const float* emb_su   = (const float*)d_in[5];
    const float* emb_tl   = (const float*)d_in[6];
    const float* emb_tu   = (const float*)d_in[7];
    float* out = (float*)d_out;

    embed_kernel<<<BB * LL, 256, 0, stream>>>(
        traj_loc, mat2, vec, traj_len, emb_sl, emb_su, emb_tl, emb_tu, out);
}